// Round 16
// baseline (173.111 us; speedup 1.0000x reference)
//
#include <hip/hip_runtime.h>
#include <hip/hip_bf16.h>

typedef __bf16 bf16x8 __attribute__((ext_vector_type(8)));
typedef float f32x4 __attribute__((ext_vector_type(4)));
typedef unsigned int u32;
typedef unsigned short u16;
typedef u32 u32x4 __attribute__((ext_vector_type(4)));
typedef u16 u16x4 __attribute__((ext_vector_type(4)));
typedef u16 u16x8 __attribute__((ext_vector_type(8)));

// manual RNE f32->bf16
__device__ __forceinline__ u16 f2bf(float x) {
  u32 u = __float_as_uint(x);
  return (u16)((u + 0x7FFFu + ((u >> 16) & 1u)) >> 16);
}
// compiler cast (hot path)
__device__ __forceinline__ u16 cvt_bf16(float x) {
  __bf16 h = (__bf16)x;
  return __builtin_bit_cast(u16, h);
}
__device__ __forceinline__ float bf2f(u16 h) {
  return __uint_as_float((u32)h << 16);
}

__device__ __forceinline__ bf16x8 ld_frag_lds(const u16* base, int byteOff) {
  u32x4 v = *(const u32x4*)((const char*)base + byteOff);
  return __builtin_bit_cast(bf16x8, v);
}
__device__ __forceinline__ bf16x8 ld_frag_glb(const u16* p) {
  u32x4 v = *(const u32x4*)p;
  return __builtin_bit_cast(bf16x8, v);
}

// ---------------------------------------------------------------------------
// prep_w (R10/R12-proven, UNCHANGED):
// wfA (128 KB): W2a K=256 N=256 as MFMA A-fragments.
// wfB2 (32 KB): W2b fragments, PI-PERMUTED k-order (pi(g,q)=q<4?4g+q:16+4g+q-4).
// ---------------------------------------------------------------------------
__global__ void prep_w_kernel(const float* __restrict__ W2a, const float* __restrict__ W2b,
                              u16* __restrict__ wfA, u16* __restrict__ wfB2) {
  int t = blockIdx.x * 256 + threadIdx.x;
  if (t < 8192) {
    int lane = t & 63;
    int ks = (t >> 6) & 7;
    int ntg = t >> 9;
    int col = (ntg << 4) + (lane & 15);
    int kb = (ks << 5) + ((lane >> 4) << 3);
#pragma unroll
    for (int q = 0; q < 8; ++q)
      wfA[t * 8 + q] = f2bf(W2a[(kb + q) * 256 + col]);
  } else if (t < 10240) {
    int t2i = t - 8192;
    int lane = t2i & 63;
    int dt = (t2i >> 6) & 3;
    int tt = (t2i >> 8) & 1;
    int w = t2i >> 9;
    int g = lane >> 4, c = lane & 15;
    int col = (dt << 4) + c;
#pragma unroll
    for (int q = 0; q < 8; ++q) {
      int pi = (q < 4) ? (g * 4 + q) : (16 + g * 4 + (q - 4));
      int n = w * 64 + tt * 32 + pi;
      wfB2[t2i * 8 + q] = f2bf(W2b[n * 64 + col]);
    }
  }
}

// emb1 -> bf16 (256 KB), trivial
__global__ __launch_bounds__(256) void prep_e1_kernel(const float* __restrict__ emb1,
                                                      u16* __restrict__ e1b) {
  int t = blockIdx.x * 256 + threadIdx.x;  // 16384 threads x 8 elems
  const float* p = emb1 + t * 8;
  float4 a0 = *(const float4*)p;
  float4 a1 = *(const float4*)(p + 4);
  u16x8 o = {f2bf(a0.x), f2bf(a0.y), f2bf(a0.z), f2bf(a0.w),
             f2bf(a1.x), f2bf(a1.y), f2bf(a1.z), f2bf(a1.w)};
  *(u16x8*)(e1b + t * 8) = o;
}

// ---------------------------------------------------------------------------
// out1: R1-proven + optional emb2->bf16 conversion write (it reads every
// element anyway; coalesced 128B rows). SEPARATE kernel (fusion thrashes:
// R4/R5/R11). Launched before out2.
// ---------------------------------------------------------------------------
__global__ __launch_bounds__(256) void out1_kernel(
    const float* __restrict__ emb1, const float* __restrict__ emb2,
    const float* __restrict__ W1a, const float* __restrict__ b1a,
    const float* __restrict__ W1b, const float* __restrict__ b1b,
    float* __restrict__ out1, u16* __restrict__ e2b) {
  int bi = blockIdx.x;
  int t = threadIdx.x;
  __shared__ float smax[4][64];
  __shared__ float smin[4][64];
  __shared__ float cat1[192];
  __shared__ float h[128];

  int d = t & 63, q = t >> 6;
  const float* base = emb2 + (size_t)bi * 256 * 64;
  float vmax = -INFINITY, vmin = INFINITY;
  if (e2b) {
    u16* eb = e2b + (size_t)bi * 256 * 64;
    for (int j = q; j < 256; j += 4) {
      float v = base[j * 64 + d];
      eb[j * 64 + d] = f2bf(v);
      vmax = fmaxf(vmax, v);
      vmin = fminf(vmin, v);
    }
  } else {
    for (int j = q; j < 256; j += 4) {
      float v = base[j * 64 + d];
      vmax = fmaxf(vmax, v);
      vmin = fminf(vmin, v);
    }
  }
  smax[q][d] = vmax;
  smin[q][d] = vmin;
  __syncthreads();
  if (t < 64) {
    float mx = fmaxf(fmaxf(smax[0][t], smax[1][t]), fmaxf(smax[2][t], smax[3][t]));
    float mn = fminf(fminf(smin[0][t], smin[1][t]), fminf(smin[2][t], smin[3][t]));
    cat1[t] = emb1[bi * 64 + t];
    cat1[64 + t] = mx;
    cat1[128 + t] = mn;
  }
  __syncthreads();
  if (t < 128) {
    float acc = b1a[t];
    for (int k = 0; k < 192; ++k) acc += cat1[k] * W1a[k * 128 + t];
    h[t] = fmaxf(acc, 0.f);
  }
  __syncthreads();
  if (t < 64) {
    float acc = b1b[t];
    for (int k = 0; k < 128; ++k) acc += h[k] * W1b[k * 64 + t];
    out1[bi * 64 + t] = acc;
  }
}

// X-plane fragment offset: 4 planes of [64 rows x 128B], swizzle ^(lr&7)<<4
__device__ __forceinline__ int xoff(int ks, int m, int lr, int lg) {
  int inner = (((m << 4) + lr) << 7) + ((ks & 1) << 6) + (lg << 4);
  return ((ks >> 1) << 13) + (inner ^ ((lr & 7) << 4));
}

// ---------------------------------------------------------------------------
// out2 DMA variant: one block = (b, i, j-tile of 64).
// STAGE = 8 global_load_lds(16B) per wave, ZERO VALU, zero reg round-trip:
//   wave w fills plane w (s0=e1[j] | s1=e2[j,i] gather | s2=e1[i] | s3=e2[i,j])
//   from bf16-preconverted e1b/e2b. Linear LDS dest + PRE-SWIZZLED per-lane
//   global source (rule #21): lane(rsub,slot) fetches row r0+rsub, byte
//   (slot*16)^(rsub*16) so linear placement == XOR-swizzled layout.
// GEMM1/GEMM2/exchange = R15's proven code (plane read offsets via xoff).
// ---------------------------------------------------------------------------
__global__ __launch_bounds__(256, 2) void out2_dma_kernel(
    const u16* __restrict__ e1b, const u16* __restrict__ e2b,
    const float* __restrict__ b2a, const float* __restrict__ b2b,
    const u16* __restrict__ wfA, const u16* __restrict__ wfB2,
    float* __restrict__ out2) {
  __shared__ __align__(16) u16 SH[16384];  // 32 KB: 4 planes x 8 KB; exchange reuses

  int blk = blockIdx.x;
  int b = blk >> 10;
  int i = (blk >> 2) & 255;
  int j0 = (blk & 3) << 6;
  int t = threadIdx.x;
  int lane = t & 63;
  int w = t >> 6;
  int lr = lane & 15;
  int lg = lane >> 4;

  // ---- stage: wave w fills plane w via 8 async DMA chunks of 1 KB ----
  {
    int rsub = lane >> 3;                 // 0..7 (== r&7 since chunks are 8-row)
    int slot = lane & 7;
    int cb = ((slot ^ rsub) << 4);        // pre-swizzled source byte offset
#pragma unroll
    for (int c = 0; c < 8; ++c) {
      int r = (c << 3) + rsub;
      const u16* srow;
      if (w == 0)      srow = e1b + (((b << 8) + j0 + r) << 6);
      else if (w == 1) srow = e2b + ((((size_t)(b << 8) + j0 + r) << 8) + i) * 64;
      else if (w == 2) srow = e1b + (((b << 8) + i) << 6);
      else             srow = e2b + ((((size_t)(b << 8) + i) << 8) + (j0 + r)) * 64;
      __builtin_amdgcn_global_load_lds(
          (const __attribute__((address_space(1))) u32*)((const char*)srow + cb),
          (__attribute__((address_space(3))) u32*)((char*)SH + (w << 13) + (c << 10)),
          16, 0, 0);
    }
  }
  __syncthreads();  // barrier drain waits vmcnt(0) -> planes complete

  // ---- GEMM1 (swapped): acc1[m][nt][e]: j = j0+16m+lr, n = 64w+16nt+4lg+e ----
  f32x4 acc1[4][4];
#pragma unroll
  for (int m = 0; m < 4; ++m)
#pragma unroll
    for (int nt = 0; nt < 4; ++nt) acc1[m][nt] = (f32x4){0.f, 0.f, 0.f, 0.f};

  bf16x8 aF[2][4], bF[2][4];
#pragma unroll
  for (int nt = 0; nt < 4; ++nt)
    bF[0][nt] = ld_frag_glb(wfA + (size_t)((((w << 2) + nt) * 8 + 0) * 64 + lane) * 8);
#pragma unroll
  for (int m = 0; m < 4; ++m)
    aF[0][m] = ld_frag_lds(SH, xoff(0, m, lr, lg));

#pragma unroll
  for (int ks = 0; ks < 8; ++ks) {
    const int cur = ks & 1;
    const int nxt = cur ^ 1;
    if (ks < 7) {
#pragma unroll
      for (int nt = 0; nt < 4; ++nt)
        bF[nxt][nt] = ld_frag_glb(wfA + (size_t)((((w << 2) + nt) * 8 + (ks + 1)) * 64 + lane) * 8);
#pragma unroll
      for (int m = 0; m < 4; ++m)
        aF[nxt][m] = ld_frag_lds(SH, xoff(ks + 1, m, lr, lg));
    }
#pragma unroll
    for (int m = 0; m < 4; ++m)
#pragma unroll
      for (int nt = 0; nt < 4; ++nt)
        acc1[m][nt] = __builtin_amdgcn_mfma_f32_16x16x32_bf16(bF[cur][nt], aF[cur][m],
                                                              acc1[m][nt], 0, 0, 0);
  }

  __syncthreads();  // X reads done; SH becomes the exchange region

  // ---- GEMM2 in registers (pi-packing), wfB2 hoisted ----
  bf16x8 wfb[8];
#pragma unroll
  for (int t2 = 0; t2 < 2; ++t2)
#pragma unroll
    for (int dt = 0; dt < 4; ++dt)
      wfb[t2 * 4 + dt] =
          ld_frag_glb(wfB2 + (size_t)(((((w << 1) + t2) << 2) + dt) * 64 + lane) * 8);

  f32x4 acc2[4][4];
#pragma unroll
  for (int m = 0; m < 4; ++m)
#pragma unroll
    for (int dt = 0; dt < 4; ++dt) acc2[m][dt] = (f32x4){0.f, 0.f, 0.f, 0.f};

#pragma unroll
  for (int t2 = 0; t2 < 2; ++t2) {
    int nbase = (w << 6) + (t2 << 5) + (lg << 2);
    float4 ba = *(const float4*)(b2a + nbase);
    float4 bb = *(const float4*)(b2a + nbase + 16);
    bf16x8 h[4];
#pragma unroll
    for (int m = 0; m < 4; ++m) {
      f32x4 pa = acc1[m][2 * t2];
      f32x4 pb = acc1[m][2 * t2 + 1];
      u16x8 hp = {cvt_bf16(fmaxf(pa[0] + ba.x, 0.f)), cvt_bf16(fmaxf(pa[1] + ba.y, 0.f)),
                  cvt_bf16(fmaxf(pa[2] + ba.z, 0.f)), cvt_bf16(fmaxf(pa[3] + ba.w, 0.f)),
                  cvt_bf16(fmaxf(pb[0] + bb.x, 0.f)), cvt_bf16(fmaxf(pb[1] + bb.y, 0.f)),
                  cvt_bf16(fmaxf(pb[2] + bb.z, 0.f)), cvt_bf16(fmaxf(pb[3] + bb.w, 0.f))};
      h[m] = __builtin_bit_cast(bf16x8, hp);
    }
#pragma unroll
    for (int dt = 0; dt < 4; ++dt)
#pragma unroll
      for (int m = 0; m < 4; ++m)
        acc2[m][dt] = __builtin_amdgcn_mfma_f32_16x16x32_bf16(wfb[t2 * 4 + dt], h[m],
                                                              acc2[m][dt], 0, 0, 0);
  }

  // ---- cross-wave reduction, BF16 partials (R12-proven) ----
  char* red = (char*)SH;
#pragma unroll
  for (int dt = 0; dt < 4; ++dt) {
    if (dt != w) {
      int s = dt - (dt > w ? 1 : 0);
#pragma unroll
      for (int m = 0; m < 4; ++m) {
        f32x4 p = acc2[m][dt];
        u16x4 o = {cvt_bf16(p[0]), cvt_bf16(p[1]), cvt_bf16(p[2]), cvt_bf16(p[3])};
        *(u16x4*)(red + (((w * 12 + s * 4 + m) << 9) + (lane << 3))) = o;
      }
    }
  }
  __syncthreads();

  f32x4 accO[4];
#pragma unroll
  for (int m = 0; m < 4; ++m) {
    accO[m] = acc2[m][0];
#pragma unroll
    for (int dt = 1; dt < 4; ++dt)
      if (w == dt) accO[m] = acc2[m][dt];
  }
#pragma unroll
  for (int wp = 0; wp < 4; ++wp) {
    if (wp != w) {
      int s = w - (w > wp ? 1 : 0);
#pragma unroll
      for (int m = 0; m < 4; ++m) {
        u16x4 o = *(const u16x4*)(red + (((wp * 12 + s * 4 + m) << 9) + (lane << 3)));
        accO[m][0] += bf2f(o[0]);
        accO[m][1] += bf2f(o[1]);
        accO[m][2] += bf2f(o[2]);
        accO[m][3] += bf2f(o[3]);
      }
    }
  }

  float4 bias2 = *(const float4*)(b2b + (w << 4) + (lg << 2));
  float* obase = out2 + (((size_t)(b << 8) + i) * 256 + j0) * 64 + (w << 4) + (lg << 2);
#pragma unroll
  for (int m = 0; m < 4; ++m) {
    float4 v = {accO[m][0] + bias2.x, accO[m][1] + bias2.y,
                accO[m][2] + bias2.z, accO[m][3] + bias2.w};
    *(float4*)(obase + (size_t)((m << 4) + lr) * 64) = v;
  }
}

// ---------------------------------------------------------------------------
// out2 fallback (R15 verbatim): used when ws_size can't hold bf16 emb2.
// ---------------------------------------------------------------------------
__global__ __launch_bounds__(256, 2) void out2_kernel(
    const float* __restrict__ emb1, const float* __restrict__ emb2,
    const float* __restrict__ b2a, const float* __restrict__ b2b,
    const u16* __restrict__ wfA, const u16* __restrict__ wfB2,
    float* __restrict__ out2) {
  __shared__ __align__(16) u16 SH[16384];

  int blk = blockIdx.x;
  int b = blk >> 10;
  int i = (blk >> 2) & 255;
  int j0 = (blk & 3) << 6;
  int t = threadIdx.x;
  int lane = t & 63;
  int w = t >> 6;
  int lr = lane & 15;
  int lg = lane >> 4;

  {
    int r = t >> 2;
    int c16 = (t & 3) << 4;
    const float* s0 = emb1 + ((b << 8) + j0 + r) * 64;
    const float* s1 = emb2 + ((((size_t)(b << 8) + j0 + r) << 8) + i) * 64;
    const float* s2 = emb1 + ((b << 8) + i) * 64;
    const float* s3 = emb2 + ((((size_t)(b << 8) + i) << 8) + (j0 + r)) * 64;
    const float* srcs[4] = {s0, s1, s2, s3};
#pragma unroll
    for (int seg = 0; seg < 4; ++seg) {
      const float* src = srcs[seg];
#pragma unroll
      for (int u = 0; u < 2; ++u) {
        int d = c16 + (u << 3);
        float4 v0 = *(const float4*)(src + d);
        float4 v1 = *(const float4*)(src + d + 4);
        u16x8 o = {cvt_bf16(v0.x), cvt_bf16(v0.y), cvt_bf16(v0.z), cvt_bf16(v0.w),
                   cvt_bf16(v1.x), cvt_bf16(v1.y), cvt_bf16(v1.z), cvt_bf16(v1.w)};
        int byteOff = (r * 512 + ((seg << 6) + d) * 2) ^ ((r & 7) << 4);
        *(u16x8*)((char*)SH + byteOff) = o;
      }
    }
  }
  __syncthreads();

  f32x4 acc1[4][4];
#pragma unroll
  for (int m = 0; m < 4; ++m)
#pragma unroll
    for (int nt = 0; nt < 4; ++nt) acc1[m][nt] = (f32x4){0.f, 0.f, 0.f, 0.f};

  bf16x8 aF[2][4], bF[2][4];
#pragma unroll
  for (int nt = 0; nt < 4; ++nt)
    bF[0][nt] = ld_frag_glb(wfA + (size_t)((((w << 2) + nt) * 8 + 0) * 64 + lane) * 8);
#pragma unroll
  for (int m = 0; m < 4; ++m)
    aF[0][m] = ld_frag_lds(SH, (((m << 4) + lr) * 512 + (lg << 4)) ^ ((lr & 7) << 4));

#pragma unroll
  for (int ks = 0; ks < 8; ++ks) {
    const int cur = ks & 1;
    const int nxt = cur ^ 1;
    if (ks < 7) {
      int kByte = ((ks + 1) << 6) + (lg << 4);
#pragma unroll
      for (int nt = 0; nt < 4; ++nt)
        bF[nxt][nt] = ld_frag_glb(wfA + (size_t)((((w << 2) + nt) * 8 + (ks + 1)) * 64 + lane) * 8);
#pragma unroll
      for (int m = 0; m < 4; ++m)
        aF[nxt][m] = ld_frag_lds(SH, (((m << 4) + lr) * 512 + kByte) ^ ((lr & 7) << 4));
    }
#pragma unroll
    for (int m = 0; m < 4; ++m)
#pragma unroll
      for (int nt = 0; nt < 4; ++nt)
        acc1[m][nt] = __builtin_amdgcn_mfma_f32_16x16x32_bf16(bF[cur][nt], aF[cur][m],
                                                              acc1[m][nt], 0, 0, 0);
  }

  __syncthreads();

  bf16x8 wfb[8];
#pragma unroll
  for (int t2 = 0; t2 < 2; ++t2)
#pragma unroll
    for (int dt = 0; dt < 4; ++dt)
      wfb[t2 * 4 + dt] =
          ld_frag_glb(wfB2 + (size_t)(((((w << 1) + t2) << 2) + dt) * 64 + lane) * 8);

  f32x4 acc2[4][4];
#pragma unroll
  for (int m = 0; m < 4; ++m)
#pragma unroll
    for (int dt = 0; dt < 4; ++dt) acc2[m][dt] = (f32x4){0.f, 0.f, 0.f, 0.f};

#pragma unroll
  for (int t2 = 0; t2 < 2; ++t2) {
    int nbase = (w << 6) + (t2 << 5) + (lg << 2);
    float4 ba = *(const float4*)(b2a + nbase);
    float4 bb = *(const float4*)(b2a + nbase + 16);
    bf16x8 h[4];
#pragma unroll
    for (int m = 0; m < 4; ++m) {
      f32x4 pa = acc1[m][2 * t2];
      f32x4 pb = acc1[m][2 * t2 + 1];
      u16x8 hp = {cvt_bf16(fmaxf(pa[0] + ba.x, 0.f)), cvt_bf16(fmaxf(pa[1] + ba.y, 0.f)),
                  cvt_bf16(fmaxf(pa[2] + ba.z, 0.f)), cvt_bf16(fmaxf(pa[3] + ba.w, 0.f)),
                  cvt_bf16(fmaxf(pb[0] + bb.x, 0.f)), cvt_bf16(fmaxf(pb[1] + bb.y, 0.f)),
                  cvt_bf16(fmaxf(pb[2] + bb.z, 0.f)), cvt_bf16(fmaxf(pb[3] + bb.w, 0.f))};
      h[m] = __builtin_bit_cast(bf16x8, hp);
    }
#pragma unroll
    for (int dt = 0; dt < 4; ++dt)
#pragma unroll
      for (int m = 0; m < 4; ++m)
        acc2[m][dt] = __builtin_amdgcn_mfma_f32_16x16x32_bf16(wfb[t2 * 4 + dt], h[m],
                                                              acc2[m][dt], 0, 0, 0);
  }

  char* red = (char*)SH;
#pragma unroll
  for (int dt = 0; dt < 4; ++dt) {
    if (dt != w) {
      int s = dt - (dt > w ? 1 : 0);
#pragma unroll
      for (int m = 0; m < 4; ++m) {
        f32x4 p = acc2[m][dt];
        u16x4 o = {cvt_bf16(p[0]), cvt_bf16(p[1]), cvt_bf16(p[2]), cvt_bf16(p[3])};
        *(u16x4*)(red + (((w * 12 + s * 4 + m) << 9) + (lane << 3))) = o;
      }
    }
  }
  __syncthreads();

  f32x4 accO[4];
#pragma unroll
  for (int m = 0; m < 4; ++m) {
    accO[m] = acc2[m][0];
#pragma unroll
    for (int dt = 1; dt < 4; ++dt)
      if (w == dt) accO[m] = acc2[m][dt];
  }
#pragma unroll
  for (int wp = 0; wp < 4; ++wp) {
    if (wp != w) {
      int s = w - (w > wp ? 1 : 0);
#pragma unroll
      for (int m = 0; m < 4; ++m) {
        u16x4 o = *(const u16x4*)(red + (((wp * 12 + s * 4 + m) << 9) + (lane << 3)));
        accO[m][0] += bf2f(o[0]);
        accO[m][1] += bf2f(o[1]);
        accO[m][2] += bf2f(o[2]);
        accO[m][3] += bf2f(o[3]);
      }
    }
  }

  float4 bias2 = *(const float4*)(b2b + (w << 4) + (lg << 2));
  float* obase = out2 + (((size_t)(b << 8) + i) * 256 + j0) * 64 + (w << 4) + (lg << 2);
#pragma unroll
  for (int m = 0; m < 4; ++m) {
    float4 v = {accO[m][0] + bias2.x, accO[m][1] + bias2.y,
                accO[m][2] + bias2.z, accO[m][3] + bias2.w};
    *(float4*)(obase + (size_t)((m << 4) + lr) * 64) = v;
  }
}

extern "C" void kernel_launch(void* const* d_in, const int* in_sizes, int n_in,
                              void* d_out, int out_size, void* d_ws, size_t ws_size,
                              hipStream_t stream) {
  const float* emb1 = (const float*)d_in[0];
  const float* emb2 = (const float*)d_in[1];
  const float* W1a  = (const float*)d_in[2];
  const float* b1a  = (const float*)d_in[3];
  const float* W1b  = (const float*)d_in[4];
  const float* b1b  = (const float*)d_in[5];
  const float* W2a  = (const float*)d_in[6];
  const float* b2a  = (const float*)d_in[7];
  const float* W2b  = (const float*)d_in[8];
  const float* b2b  = (const float*)d_in[9];

  float* out = (float*)d_out;
  u16* wfA  = (u16*)d_ws;                  // 65536 u16  = 128 KB
  u16* wfB2 = wfA + 65536;                 // 16384 u16  =  32 KB
  u16* e1b  = wfB2 + 16384;                // 131072 u16 = 256 KB
  u16* e2b  = e1b + 131072;                // 33554432 u16 = 64 MB
  size_t need = ((size_t)65536 + 16384 + 131072 + 33554432) * 2;
  bool dma = ws_size >= need;

  prep_w_kernel<<<40, 256, 0, stream>>>(W2a, W2b, wfA, wfB2);
  if (dma) {
    prep_e1_kernel<<<64, 256, 0, stream>>>(emb1, e1b);
    // out1 converts emb2->bf16 while doing its reduction; also L3-warms
    out1_kernel<<<2048, 256, 0, stream>>>(emb1, emb2, W1a, b1a, W1b, b1b,
                                          out, e2b);
    out2_dma_kernel<<<8192, 256, 0, stream>>>(e1b, e2b, b2a, b2b, wfA, wfB2,
                                              out + 8 * 256 * 64);
  } else {
    out1_kernel<<<2048, 256, 0, stream>>>(emb1, emb2, W1a, b1a, W1b, b1b,
                                          out, nullptr);
    out2_kernel<<<8192, 256, 0, stream>>>(emb1, emb2, b2a, b2b, wfA, wfB2,
                                          out + 8 * 256 * 64);
  }
}

// Round 17
// 168.678 us; speedup vs baseline: 1.0263x; 1.0263x over previous
//
#include <hip/hip_runtime.h>
#include <hip/hip_bf16.h>

typedef __bf16 bf16x8 __attribute__((ext_vector_type(8)));
typedef float f32x4 __attribute__((ext_vector_type(4)));
typedef unsigned int u32;
typedef unsigned short u16;
typedef u32 u32x4 __attribute__((ext_vector_type(4)));
typedef u16 u16x4 __attribute__((ext_vector_type(4)));
typedef u16 u16x8 __attribute__((ext_vector_type(8)));

__device__ __forceinline__ u16 f2bf(float x) {
  u32 u = __float_as_uint(x);
  return (u16)((u + 0x7FFFu + ((u >> 16) & 1u)) >> 16);
}
__device__ __forceinline__ u16 cvt_bf16(float x) {
  __bf16 h = (__bf16)x;
  return __builtin_bit_cast(u16, h);
}
__device__ __forceinline__ float bf2f(u16 h) {
  return __uint_as_float((u32)h << 16);
}
__device__ __forceinline__ bf16x8 ld_frag_lds(const u16* base, int byteOff) {
  u32x4 v = *(const u32x4*)((const char*)base + byteOff);
  return __builtin_bit_cast(bf16x8, v);
}
__device__ __forceinline__ bf16x8 ld_frag_glb(const u16* p) {
  u32x4 v = *(const u32x4*)p;
  return __builtin_bit_cast(bf16x8, v);
}

// ---------------------------------------------------------------------------
// prep_w (R10/R12-proven, UNCHANGED).
// ---------------------------------------------------------------------------
__global__ void prep_w_kernel(const float* __restrict__ W2a, const float* __restrict__ W2b,
                              u16* __restrict__ wfA, u16* __restrict__ wfB2) {
  int t = blockIdx.x * 256 + threadIdx.x;
  if (t < 8192) {
    int lane = t & 63;
    int ks = (t >> 6) & 7;
    int ntg = t >> 9;
    int col = (ntg << 4) + (lane & 15);
    int kb = (ks << 5) + ((lane >> 4) << 3);
#pragma unroll
    for (int q = 0; q < 8; ++q)
      wfA[t * 8 + q] = f2bf(W2a[(kb + q) * 256 + col]);
  } else if (t < 10240) {
    int t2i = t - 8192;
    int lane = t2i & 63;
    int dt = (t2i >> 6) & 3;
    int tt = (t2i >> 8) & 1;
    int w = t2i >> 9;
    int g = lane >> 4, c = lane & 15;
    int col = (dt << 4) + c;
#pragma unroll
    for (int q = 0; q < 8; ++q) {
      int pi = (q < 4) ? (g * 4 + q) : (16 + g * 4 + (q - 4));
      int n = w * 64 + tt * 32 + pi;
      wfB2[t2i * 8 + q] = f2bf(W2b[n * 64 + col]);
    }
  }
}

__global__ __launch_bounds__(256) void prep_e1_kernel(const float* __restrict__ emb1,
                                                      u16* __restrict__ e1b) {
  int t = blockIdx.x * 256 + threadIdx.x;
  const float* p = emb1 + t * 8;
  float4 a0 = *(const float4*)p;
  float4 a1 = *(const float4*)(p + 4);
  u16x8 o = {f2bf(a0.x), f2bf(a0.y), f2bf(a0.z), f2bf(a0.w),
             f2bf(a1.x), f2bf(a1.y), f2bf(a1.z), f2bf(a1.w)};
  *(u16x8*)(e1b + t * 8) = o;
}

// ---------------------------------------------------------------------------
// out1cvt: VECTORIZED convert + reduce + MLP. One block per (b,i).
// Pass p: thread (rsub=t>>3, cg=t&7) reads row p*32+rsub, cols cg*8..+8
// (32B/lane coalesced f32), writes u16x8 e2b (16B/lane), accumulates
// max/min on the F32 values (out1 semantics identical to reference).
// Two-stage reduce: 8 regs -> LDS[32][64] -> 64-thread final.
// R16's version read 4B/lane and wrote 2B/lane (Common-mistake #2): ~50us;
// this is the same 201 MB at proper width: ~32-38us expected.
// ---------------------------------------------------------------------------
__global__ __launch_bounds__(256) void out1cvt_kernel(
    const float* __restrict__ emb1, const float* __restrict__ emb2,
    const float* __restrict__ W1a, const float* __restrict__ b1a,
    const float* __restrict__ W1b, const float* __restrict__ b1b,
    float* __restrict__ out1, u16* __restrict__ e2b) {
  __shared__ float smax[32 * 64];
  __shared__ float smin[32 * 64];
  __shared__ float cat1[192];
  __shared__ float h[128];

  int bi = blockIdx.x;
  int t = threadIdx.x;
  int rsub = t >> 3;
  int c0 = (t & 7) << 3;
  const float* base = emb2 + (size_t)bi * 16384;
  u16* eb = e2b + (size_t)bi * 16384;

  float vmax8[8], vmin8[8];
#pragma unroll
  for (int e = 0; e < 8; ++e) { vmax8[e] = -INFINITY; vmin8[e] = INFINITY; }

#pragma unroll
  for (int p = 0; p < 8; ++p) {
    int r = (p << 5) + rsub;
    const float* row = base + r * 64 + c0;
    float4 a0 = *(const float4*)row;
    float4 a1 = *(const float4*)(row + 4);
    u16x8 o = {f2bf(a0.x), f2bf(a0.y), f2bf(a0.z), f2bf(a0.w),
               f2bf(a1.x), f2bf(a1.y), f2bf(a1.z), f2bf(a1.w)};
    *(u16x8*)(eb + r * 64 + c0) = o;
    float v[8] = {a0.x, a0.y, a0.z, a0.w, a1.x, a1.y, a1.z, a1.w};
#pragma unroll
    for (int e = 0; e < 8; ++e) {
      vmax8[e] = fmaxf(vmax8[e], v[e]);
      vmin8[e] = fminf(vmin8[e], v[e]);
    }
  }
#pragma unroll
  for (int e = 0; e < 8; ++e) {
    smax[rsub * 64 + c0 + e] = vmax8[e];
    smin[rsub * 64 + c0 + e] = vmin8[e];
  }
  __syncthreads();
  if (t < 64) {
    float mx = smax[t], mn = smin[t];
#pragma unroll 8
    for (int r = 1; r < 32; ++r) {
      mx = fmaxf(mx, smax[r * 64 + t]);
      mn = fminf(mn, smin[r * 64 + t]);
    }
    cat1[t] = emb1[bi * 64 + t];
    cat1[64 + t] = mx;
    cat1[128 + t] = mn;
  }
  __syncthreads();
  if (t < 128) {
    float acc = b1a[t];
    for (int k = 0; k < 192; ++k) acc += cat1[k] * W1a[k * 128 + t];
    h[t] = fmaxf(acc, 0.f);
  }
  __syncthreads();
  if (t < 64) {
    float acc = b1b[t];
    for (int k = 0; k < 128; ++k) acc += h[k] * W1b[k * 64 + t];
    out1[bi * 64 + t] = acc;
  }
}

// plain out1 (fallback path, R1-proven)
__global__ __launch_bounds__(256) void out1_kernel(
    const float* __restrict__ emb1, const float* __restrict__ emb2,
    const float* __restrict__ W1a, const float* __restrict__ b1a,
    const float* __restrict__ W1b, const float* __restrict__ b1b,
    float* __restrict__ out1) {
  int bi = blockIdx.x;
  int t = threadIdx.x;
  __shared__ float smax[4][64];
  __shared__ float smin[4][64];
  __shared__ float cat1[192];
  __shared__ float h[128];
  int d = t & 63, q = t >> 6;
  const float* base = emb2 + (size_t)bi * 256 * 64;
  float vmax = -INFINITY, vmin = INFINITY;
  for (int j = q; j < 256; j += 4) {
    float v = base[j * 64 + d];
    vmax = fmaxf(vmax, v);
    vmin = fminf(vmin, v);
  }
  smax[q][d] = vmax;
  smin[q][d] = vmin;
  __syncthreads();
  if (t < 64) {
    float mx = fmaxf(fmaxf(smax[0][t], smax[1][t]), fmaxf(smax[2][t], smax[3][t]));
    float mn = fminf(fminf(smin[0][t], smin[1][t]), fminf(smin[2][t], smin[3][t]));
    cat1[t] = emb1[bi * 64 + t];
    cat1[64 + t] = mx;
    cat1[128 + t] = mn;
  }
  __syncthreads();
  if (t < 128) {
    float acc = b1a[t];
    for (int k = 0; k < 192; ++k) acc += cat1[k] * W1a[k * 128 + t];
    h[t] = fmaxf(acc, 0.f);
  }
  __syncthreads();
  if (t < 64) {
    float acc = b1b[t];
    for (int k = 0; k < 128; ++k) acc += h[k] * W1b[k * 64 + t];
    out1[bi * 64 + t] = acc;
  }
}

__device__ __forceinline__ int xoff(int ks, int m, int lr, int lg) {
  int inner = (((m << 4) + lr) << 7) + ((ks & 1) << 6) + (lg << 4);
  return ((ks >> 1) << 13) + (inner ^ ((lr & 7) << 4));
}

// ---------------------------------------------------------------------------
// out2 DMA, 2-GENERATION blocks: block = (b, i, j-half of 128) -> 4096 blocks.
// gen g handles j0 = jh*128 + g*64. X double-buffer X0@0 / X1@32K (32 KB each,
// 4 planes x 8 KB). Gen-1's DMA is ISSUED before gen-0's GEMM1 -> its latency
// hides under gen-0 compute (drained by the post-GEMM1 barrier). wfB2 frags +
// bias hoisted across gens; wfA L2 stream amortized 2x. Exchange (bf16, 24 KB)
// lives inside the CURRENT (dead) X buffer -> LDS 64 KB, 2 blocks/CU.
// ---------------------------------------------------------------------------
__global__ __launch_bounds__(256, 2) void out2_dma_kernel(
    const u16* __restrict__ e1b, const u16* __restrict__ e2b,
    const float* __restrict__ b2a, const float* __restrict__ b2b,
    const u16* __restrict__ wfA, const u16* __restrict__ wfB2,
    float* __restrict__ out2) {
  __shared__ __align__(16) u16 SH[32768];  // 64 KB: X0 [0,32K), X1 [32K,64K)

  int blk = blockIdx.x;
  int b = blk >> 9;
  int i = (blk >> 1) & 255;
  int jh = blk & 1;
  int t = threadIdx.x;
  int lane = t & 63;
  int w = t >> 6;
  int lr = lane & 15;
  int lg = lane >> 4;

  // ---- stage issue: wave w fills plane w of buffer XB for tile j0 ----
  int rsub = lane >> 3;
  int slot = lane & 7;
  int cb = ((slot ^ rsub) << 4);  // pre-swizzled source byte offset
  auto stage = [&](int XB, int j0) {
#pragma unroll
    for (int c = 0; c < 8; ++c) {
      int r = (c << 3) + rsub;
      const u16* srow;
      if (w == 0)      srow = e1b + (((b << 8) + j0 + r) << 6);
      else if (w == 1) srow = e2b + ((((size_t)(b << 8) + j0 + r) << 8) + i) * 64;
      else if (w == 2) srow = e1b + (((b << 8) + i) << 6);
      else             srow = e2b + ((((size_t)(b << 8) + i) << 8) + (j0 + r)) * 64;
      __builtin_amdgcn_global_load_lds(
          (const __attribute__((address_space(1))) u32*)((const char*)srow + cb),
          (__attribute__((address_space(3))) u32*)((char*)SH + XB + (w << 13) + (c << 10)),
          16, 0, 0);
    }
  };

  // hoisted across gens
  bf16x8 wfb[8];
#pragma unroll
  for (int t2 = 0; t2 < 2; ++t2)
#pragma unroll
    for (int dt = 0; dt < 4; ++dt)
      wfb[t2 * 4 + dt] =
          ld_frag_glb(wfB2 + (size_t)(((((w << 1) + t2) << 2) + dt) * 64 + lane) * 8);
  float4 ba0 = *(const float4*)(b2a + (w << 6) + (lg << 2));
  float4 bb0 = *(const float4*)(b2a + (w << 6) + 16 + (lg << 2));
  float4 ba1 = *(const float4*)(b2a + (w << 6) + 32 + (lg << 2));
  float4 bb1 = *(const float4*)(b2a + (w << 6) + 48 + (lg << 2));
  float4 bias2 = *(const float4*)(b2b + (w << 4) + (lg << 2));

  int j0a = (jh << 7);
  int j0b = (jh << 7) + 64;

  stage(0, j0a);       // gen0 X
  __syncthreads();     // X0 ready
  stage(32768, j0b);   // gen1 X: rides under gen0 compute

  auto gen = [&](int XB, int j0) {
    const u16* X = (const u16*)((const char*)SH + XB);
    // ---- GEMM1 (swapped): acc1[m][nt][e]: j = j0+16m+lr, n = 64w+16nt+4lg+e ----
    f32x4 acc1[4][4];
#pragma unroll
    for (int m = 0; m < 4; ++m)
#pragma unroll
      for (int nt = 0; nt < 4; ++nt) acc1[m][nt] = (f32x4){0.f, 0.f, 0.f, 0.f};

#pragma unroll
    for (int ks = 0; ks < 8; ++ks) {
      bf16x8 a[4];
#pragma unroll
      for (int m = 0; m < 4; ++m) a[m] = ld_frag_lds(X, xoff(ks, m, lr, lg));
      bf16x8 bw[4];
#pragma unroll
      for (int nt = 0; nt < 4; ++nt)
        bw[nt] = ld_frag_glb(wfA + (size_t)((((w << 2) + nt) * 8 + ks) * 64 + lane) * 8);
#pragma unroll
      for (int m = 0; m < 4; ++m)
#pragma unroll
        for (int nt = 0; nt < 4; ++nt)
          acc1[m][nt] = __builtin_amdgcn_mfma_f32_16x16x32_bf16(bw[nt], a[m], acc1[m][nt], 0, 0, 0);
    }
    __syncthreads();  // X(cur) reads done; also drains any in-flight DMA

    // ---- GEMM2 in registers (pi-packing) ----
    f32x4 acc2[4][4];
#pragma unroll
    for (int m = 0; m < 4; ++m)
#pragma unroll
      for (int dt = 0; dt < 4; ++dt) acc2[m][dt] = (f32x4){0.f, 0.f, 0.f, 0.f};

#pragma unroll
    for (int t2 = 0; t2 < 2; ++t2) {
      float4 ba = t2 ? ba1 : ba0;
      float4 bb = t2 ? bb1 : bb0;
      bf16x8 h[4];
#pragma unroll
      for (int m = 0; m < 4; ++m) {
        f32x4 pa = acc1[m][2 * t2];
        f32x4 pb = acc1[m][2 * t2 + 1];
        u16x8 hp = {cvt_bf16(fmaxf(pa[0] + ba.x, 0.f)), cvt_bf16(fmaxf(pa[1] + ba.y, 0.f)),
                    cvt_bf16(fmaxf(pa[2] + ba.z, 0.f)), cvt_bf16(fmaxf(pa[3] + ba.w, 0.f)),
                    cvt_bf16(fmaxf(pb[0] + bb.x, 0.f)), cvt_bf16(fmaxf(pb[1] + bb.y, 0.f)),
                    cvt_bf16(fmaxf(pb[2] + bb.z, 0.f)), cvt_bf16(fmaxf(pb[3] + bb.w, 0.f))};
        h[m] = __builtin_bit_cast(bf16x8, hp);
      }
#pragma unroll
      for (int dt = 0; dt < 4; ++dt)
#pragma unroll
        for (int m = 0; m < 4; ++m)
          acc2[m][dt] = __builtin_amdgcn_mfma_f32_16x16x32_bf16(wfb[t2 * 4 + dt], h[m],
                                                                acc2[m][dt], 0, 0, 0);
    }

    // ---- bf16 partial exchange inside the dead X(cur) region ----
    char* red = (char*)SH + XB;
#pragma unroll
    for (int dt = 0; dt < 4; ++dt) {
      if (dt != w) {
        int s = dt - (dt > w ? 1 : 0);
#pragma unroll
        for (int m = 0; m < 4; ++m) {
          f32x4 p = acc2[m][dt];
          u16x4 o = {cvt_bf16(p[0]), cvt_bf16(p[1]), cvt_bf16(p[2]), cvt_bf16(p[3])};
          *(u16x4*)(red + (((w * 12 + s * 4 + m) << 9) + (lane << 3))) = o;
        }
      }
    }
    __syncthreads();

    f32x4 accO[4];
#pragma unroll
    for (int m = 0; m < 4; ++m) {
      accO[m] = acc2[m][0];
#pragma unroll
      for (int dt = 1; dt < 4; ++dt)
        if (w == dt) accO[m] = acc2[m][dt];
    }
#pragma unroll
    for (int wp = 0; wp < 4; ++wp) {
      if (wp != w) {
        int s = w - (w > wp ? 1 : 0);
#pragma unroll
        for (int m = 0; m < 4; ++m) {
          u16x4 o = *(const u16x4*)(red + (((wp * 12 + s * 4 + m) << 9) + (lane << 3)));
          accO[m][0] += bf2f(o[0]);
          accO[m][1] += bf2f(o[1]);
          accO[m][2] += bf2f(o[2]);
          accO[m][3] += bf2f(o[3]);
        }
      }
    }

    float* obase = out2 + (((size_t)(b << 8) + i) * 256 + j0) * 64 + (w << 4) + (lg << 2);
#pragma unroll
    for (int m = 0; m < 4; ++m) {
      float4 v = {accO[m][0] + bias2.x, accO[m][1] + bias2.y,
                  accO[m][2] + bias2.z, accO[m][3] + bias2.w};
      *(float4*)(obase + (size_t)((m << 4) + lr) * 64) = v;
    }
  };

  gen(0, j0a);
  __syncthreads();  // gen0 exchange reads done before reusing anything
  gen(32768, j0b);
}

// ---------------------------------------------------------------------------
// out2 fallback (R15 verbatim, for small ws).
// ---------------------------------------------------------------------------
__global__ __launch_bounds__(256, 2) void out2_kernel(
    const float* __restrict__ emb1, const float* __restrict__ emb2,
    const float* __restrict__ b2a, const float* __restrict__ b2b,
    const u16* __restrict__ wfA, const u16* __restrict__ wfB2,
    float* __restrict__ out2) {
  __shared__ __align__(16) u16 SH[16384];
  int blk = blockIdx.x;
  int b = blk >> 10;
  int i = (blk >> 2) & 255;
  int j0 = (blk & 3) << 6;
  int t = threadIdx.x;
  int lane = t & 63;
  int w = t >> 6;
  int lr = lane & 15;
  int lg = lane >> 4;
  {
    int r = t >> 2;
    int c16 = (t & 3) << 4;
    const float* s0 = emb1 + ((b << 8) + j0 + r) * 64;
    const float* s1 = emb2 + ((((size_t)(b << 8) + j0 + r) << 8) + i) * 64;
    const float* s2 = emb1 + ((b << 8) + i) * 64;
    const float* s3 = emb2 + ((((size_t)(b << 8) + i) << 8) + (j0 + r)) * 64;
    const float* srcs[4] = {s0, s1, s2, s3};
#pragma unroll
    for (int seg = 0; seg < 4; ++seg) {
      const float* src = srcs[seg];
#pragma unroll
      for (int u = 0; u < 2; ++u) {
        int d = c16 + (u << 3);
        float4 v0 = *(const float4*)(src + d);
        float4 v1 = *(const float4*)(src + d + 4);
        u16x8 o = {cvt_bf16(v0.x), cvt_bf16(v0.y), cvt_bf16(v0.z), cvt_bf16(v0.w),
                   cvt_bf16(v1.x), cvt_bf16(v1.y), cvt_bf16(v1.z), cvt_bf16(v1.w)};
        int byteOff = (r * 512 + ((seg << 6) + d) * 2) ^ ((r & 7) << 4);
        *(u16x8*)((char*)SH + byteOff) = o;
      }
    }
  }
  __syncthreads();
  f32x4 acc1[4][4];
#pragma unroll
  for (int m = 0; m < 4; ++m)
#pragma unroll
    for (int nt = 0; nt < 4; ++nt) acc1[m][nt] = (f32x4){0.f, 0.f, 0.f, 0.f};
#pragma unroll
  for (int ks = 0; ks < 8; ++ks) {
    int kByte = (ks << 6) + (lg << 4);
    bf16x8 a[4];
#pragma unroll
    for (int m = 0; m < 4; ++m)
      a[m] = ld_frag_lds(SH, (((m << 4) + lr) * 512 + kByte) ^ ((lr & 7) << 4));
    bf16x8 bw[4];
#pragma unroll
    for (int nt = 0; nt < 4; ++nt)
      bw[nt] = ld_frag_glb(wfA + (size_t)((((w << 2) + nt) * 8 + ks) * 64 + lane) * 8);
#pragma unroll
    for (int m = 0; m < 4; ++m)
#pragma unroll
      for (int nt = 0; nt < 4; ++nt)
        acc1[m][nt] = __builtin_amdgcn_mfma_f32_16x16x32_bf16(bw[nt], a[m], acc1[m][nt], 0, 0, 0);
  }
  __syncthreads();
  bf16x8 wfb[8];
#pragma unroll
  for (int t2 = 0; t2 < 2; ++t2)
#pragma unroll
    for (int dt = 0; dt < 4; ++dt)
      wfb[t2 * 4 + dt] =
          ld_frag_glb(wfB2 + (size_t)(((((w << 1) + t2) << 2) + dt) * 64 + lane) * 8);
  f32x4 acc2[4][4];
#pragma unroll
  for (int m = 0; m < 4; ++m)
#pragma unroll
    for (int dt = 0; dt < 4; ++dt) acc2[m][dt] = (f32x4){0.f, 0.f, 0.f, 0.f};
#pragma unroll
  for (int t2 = 0; t2 < 2; ++t2) {
    int nbase = (w << 6) + (t2 << 5) + (lg << 2);
    float4 ba = *(const float4*)(b2a + nbase);
    float4 bb = *(const float4*)(b2a + nbase + 16);
    bf16x8 h[4];
#pragma unroll
    for (int m = 0; m < 4; ++m) {
      f32x4 pa = acc1[m][2 * t2];
      f32x4 pb = acc1[m][2 * t2 + 1];
      u16x8 hp = {cvt_bf16(fmaxf(pa[0] + ba.x, 0.f)), cvt_bf16(fmaxf(pa[1] + ba.y, 0.f)),
                  cvt_bf16(fmaxf(pa[2] + ba.z, 0.f)), cvt_bf16(fmaxf(pa[3] + ba.w, 0.f)),
                  cvt_bf16(fmaxf(pb[0] + bb.x, 0.f)), cvt_bf16(fmaxf(pb[1] + bb.y, 0.f)),
                  cvt_bf16(fmaxf(pb[2] + bb.z, 0.f)), cvt_bf16(fmaxf(pb[3] + bb.w, 0.f))};
      h[m] = __builtin_bit_cast(bf16x8, hp);
    }
#pragma unroll
    for (int dt = 0; dt < 4; ++dt)
#pragma unroll
      for (int m = 0; m < 4; ++m)
        acc2[m][dt] = __builtin_amdgcn_mfma_f32_16x16x32_bf16(wfb[t2 * 4 + dt], h[m],
                                                              acc2[m][dt], 0, 0, 0);
  }
  char* red = (char*)SH;
#pragma unroll
  for (int dt = 0; dt < 4; ++dt) {
    if (dt != w) {
      int s = dt - (dt > w ? 1 : 0);
#pragma unroll
      for (int m = 0; m < 4; ++m) {
        f32x4 p = acc2[m][dt];
        u16x4 o = {cvt_bf16(p[0]), cvt_bf16(p[1]), cvt_bf16(p[2]), cvt_bf16(p[3])};
        *(u16x4*)(red + (((w * 12 + s * 4 + m) << 9) + (lane << 3))) = o;
      }
    }
  }
  __syncthreads();
  f32x4 accO[4];
#pragma unroll
  for (int m = 0; m < 4; ++m) {
    accO[m] = acc2[m][0];
#pragma unroll
    for (int dt = 1; dt < 4; ++dt)
      if (w == dt) accO[m] = acc2[m][dt];
  }
#pragma unroll
  for (int wp = 0; wp < 4; ++wp) {
    if (wp != w) {
      int s = w - (w > wp ? 1 : 0);
#pragma unroll
      for (int m = 0; m < 4; ++m) {
        u16x4 o = *(const u16x4*)(red + (((wp * 12 + s * 4 + m) << 9) + (lane << 3)));
        accO[m][0] += bf2f(o[0]);
        accO[m][1] += bf2f(o[1]);
        accO[m][2] += bf2f(o[2]);
        accO[m][3] += bf2f(o[3]);
      }
    }
  }
  float4 bias2 = *(const float4*)(b2b + (w << 4) + (lg << 2));
  float* obase = out2 + (((size_t)(b << 8) + i) * 256 + j0) * 64 + (w << 4) + (lg << 2);
#pragma unroll
  for (int m = 0; m < 4; ++m) {
    float4 v = {accO[m][0] + bias2.x, accO[m][1] + bias2.y,
                accO[m][2] + bias2.z, accO[m][3] + bias2.w};
    *(float4*)(obase + (size_t)((m << 4) + lr) * 64) = v;
  }
}

extern "C" void kernel_launch(void* const* d_in, const int* in_sizes, int n_in,
                              void* d_out, int out_size, void* d_ws, size_t ws_size,
                              hipStream_t stream) {
  const float* emb1 = (const float*)d_in[0];
  const float* emb2 = (const float*)d_in[1];
  const float* W1a  = (const float*)d_in[2];
  const float* b1a  = (const float*)d_in[3];
  const float* W1b  = (const float*)d_in[4];
  const float* b1b  = (const float*)d_in[5];
  const float* W2a  = (const float*)d_in[6];
  const float* b2a  = (const float*)d_in[7];
  const float* W2b  = (const float*)d_in[8];
  const float* b2b  = (const float*)d_in[9];

  float* out = (float*)d_out;
  u16* wfA  = (u16*)d_ws;                  // 128 KB
  u16* wfB2 = wfA + 65536;                 //  32 KB
  u16* e1b  = wfB2 + 16384;                // 256 KB
  u16* e2b  = e1b + 131072;                //  64 MB
  size_t need = ((size_t)65536 + 16384 + 131072 + 33554432) * 2;
  bool dma = ws_size >= need;

  prep_w_kernel<<<40, 256, 0, stream>>>(W2a, W2b, wfA, wfB2);
  if (dma) {
    prep_e1_kernel<<<64, 256, 0, stream>>>(emb1, e1b);
    out1cvt_kernel<<<2048, 256, 0, stream>>>(emb1, emb2, W1a, b1a, W1b, b1b,
                                             out, e2b);
    out2_dma_kernel<<<4096, 256, 0, stream>>>(e1b, e2b, b2a, b2b, wfA, wfB2,
                                              out + 8 * 256 * 64);
  } else {
    out1_kernel<<<2048, 256, 0, stream>>>(emb1, emb2, W1a, b1a, W1b, b1b, out);
    out2_kernel<<<8192, 256, 0, stream>>>(emb1, emb2, b2a, b2b, wfA, wfB2,
                                          out + 8 * 256 * 64);
  }
}